// Round 1
// baseline (221.471 us; speedup 1.0000x reference)
//
#include <hip/hip_runtime.h>
#include <math.h>

// Problem constants (fixed by setup_inputs)
#define BATCH 8
#define CH    256
#define H     128
#define W     128
#define PLANE (H * W)            // 16384
#define NPIX  (BATCH * PLANE)    // 131072
#define NSHIFT 12                // symmetric half of the 24 shifts
#define NMAPS  13                // 12 shifted dots + normsq
#define NCHUNK 4                 // channel chunks
#define CPC    (CH / NCHUNK)     // 64 channels per chunk
#define CSTRIDE (NMAPS * NPIX)   // floats per chunk slice (1703936)

// 12 "positive" shifts: dy>0 or (dy==0 && dx>0). Negatives recovered by symmetry.
static __device__ __constant__ int S_DY[NSHIFT] = {0,0,1,1,1,1,1,2,2,2,2,2};
static __device__ __constant__ int S_DX[NSHIFT] = {1,2,-2,-1,0,1,2,-2,-1,0,1,2};

#define NCORRB (BATCH * 32 * NCHUNK)             // 1024 corr blocks (4/CU)
#define NSTATB (BATCH * 64)                      // 512 stats blocks

__device__ __forceinline__ void fma4(float& acc, const float4& a, const float4& b) {
    acc = fmaf(a.x, b.x, acc);
    acc = fmaf(a.y, b.y, acc);
    acc = fmaf(a.z, b.z, acc);
    acc = fmaf(a.w, b.w, acc);
}

// ---------------------------------------------------------------------------
// Kernel P: tiny init only. comb needs NO zeroing anymore: every
// (chunk, map, pixel) is written exactly once by plain store in k_corr.
// ---------------------------------------------------------------------------
__global__ __launch_bounds__(64) void k_prep(int* __restrict__ cnt,
                                             int* __restrict__ inc,
                                             float* __restrict__ out) {
    int t = threadIdx.x;
    if (t < 8) { cnt[t] = 0; inc[t] = 0; }
    if (t == 0) out[0] = 0.0f;
}

// ---------------------------------------------------------------------------
// Kernel C: fused correlation + per-image stats.
// Blocks [0, NCORRB): correlation. Grid decode: chunk(4) | tile(32) | b(8).
//   256 thr; each thread computes 2 adjacent output rows (block covers 4
//   rows, stages 6 rows x 4 channels as float4-per-pixel in LDS — this read
//   pattern measured 0 LDS bank conflicts in R3/R4).
//   Register-prefetch pipeline: next quad's 12 global loads issue during the
//   current quad's compute phase, consumed at the next ds_write.
//   Epilogue: PLAIN coalesced stores into the per-chunk slice
//   comb[chunk][map][pix] — single writer per address, no atomics, no
//   zero-init dependency (R5 change: previous version did 6.8M 4-contender
//   atomicAdds into a shared slice).
// Blocks [NCORRB, NCORRB+NSTATB): per-image cnt/inc stats.
// __launch_bounds__(256,4): 128-VGPR budget so the 26 accumulators + 12
// prefetch regs stay in arch VGPRs.
// ---------------------------------------------------------------------------
__global__ __launch_bounds__(256, 4) void k_corr(const float* __restrict__ er,
                                                 const int* __restrict__ seg,
                                                 const int* __restrict__ gtb,
                                                 float* __restrict__ comb,
                                                 int* __restrict__ cnt,
                                                 int* __restrict__ inc) {
    __shared__ float4 lds[6][132];   // 6 staged rows, x padded by 2 each side
    int t = threadIdx.x;

    if (blockIdx.x >= NCORRB) {
        // ---- stats path ----
        int blk2 = blockIdx.x - NCORRB;
        int b = blk2 >> 6;
        int i = (blk2 & 63) * 256 + t;
        int my_cnt = 0, my_any = 0;
        {
            int s = seg[b * PLANE + i];
            int g = gtb[b * PLANE + i];
            int s0 = (s == 255) ? 0 : s;
            int g0 = (g == 255) ? 0 : g;
            if (s0 > 0 && g0 > 0) {
                my_any = 1;
                int y = i >> 7, x = i & 127;
                if (y >= 2 && y < H - 2 && x >= 2 && x < W - 2) my_cnt = 1;
            }
        }
        for (int o = 32; o > 0; o >>= 1) {
            my_cnt += __shfl_down(my_cnt, o, 64);
            my_any |= __shfl_down(my_any, o, 64);
        }
        __shared__ int sc[4], sa[4];
        int lane = t & 63, wid = t >> 6;
        if (lane == 0) { sc[wid] = my_cnt; sa[wid] = my_any; }
        __syncthreads();
        if (t == 0) {
            int c = sc[0] + sc[1] + sc[2] + sc[3];
            int a = sa[0] | sa[1] | sa[2] | sa[3];
            if (c) atomicAdd(&cnt[b], c);
            if (a) atomicOr(&inc[b], 1);
        }
        return;
    }

    // ---- correlation path ----
    int blk = blockIdx.x;
    int chunk = blk & 3;
    int tile  = (blk >> 2) & 31;
    int b     = blk >> 7;
    int y0 = tile * 4;               // block covers output rows y0..y0+3
    int c0 = chunk * CPC;
    int r = t >> 7;                  // thread handles output rows y0+2r, y0+2r+1
    int x = t & 127;

    // zero the x-pad slots once (first in-loop barrier makes them visible)
    if (t < 24) {
        int row = t >> 2, col = t & 3;
        int xs = (col < 2) ? col : (col + 128);   // 0,1,130,131
        lds[row][xs] = make_float4(0.f, 0.f, 0.f, 0.f);
    }

    float accA[13], accB[13];
#pragma unroll
    for (int i = 0; i < 13; i++) { accA[i] = 0.0f; accB[i] = 0.0f; }

    const float* base = er + (size_t)b * CH * PLANE;

    // prefetch registers: 3 stage slots x 4 channels
    float pf[3][4];
    auto load_quad = [&](int c) {
#pragma unroll
        for (int k = 0; k < 3; ++k) {
            int s = t + k * 256;         // 0..767
            int row = s >> 7;            // 0..5
            int xs = s & 127;
            int y = y0 + row;
            if (y < H) {
                const float* p0 = base + (size_t)c * PLANE + y * W + xs;
                pf[k][0] = p0[0];
                pf[k][1] = p0[PLANE];
                pf[k][2] = p0[2 * PLANE];
                pf[k][3] = p0[3 * PLANE];
            } else {
                pf[k][0] = 0.f; pf[k][1] = 0.f; pf[k][2] = 0.f; pf[k][3] = 0.f;
            }
        }
    };

    load_quad(c0);
    const int iters = CPC / 4;       // 16
    for (int it = 0; it < iters; ++it) {
        __syncthreads();   // prior iter's LDS reads done
        // commit prefetched quad to LDS (vmcnt wait lands here, after overlap)
#pragma unroll
        for (int k = 0; k < 3; ++k) {
            int s = t + k * 256;
            int row = s >> 7;
            int xs = s & 127;
            lds[row][xs + 2] = make_float4(pf[k][0], pf[k][1], pf[k][2], pf[k][3]);
        }
        __syncthreads();
        if (it + 1 < iters) load_quad(c0 + 4 * (it + 1));   // overlaps compute below

        const float4* lp = &lds[2 * r][x + 2];
        float4 cA = lp[0];               // (rel row 0, dx 0)
        float4 cB = lp[132];             // (rel row 1, dx 0)
        // rel row 0: dx {0,1,2} -> accA[0..2]
        {
            float4 v1 = lp[1], v2 = lp[2];
            fma4(accA[0], cA, cA);
            fma4(accA[1], cA, v1);
            fma4(accA[2], cA, v2);
        }
        // rel row 1: dx {-2..2} -> accA[3..7]; accB[0..2] (dx 0,1,2)
        {
            float4 m2 = lp[130], m1 = lp[131], p1 = lp[133], p2 = lp[134];
            fma4(accA[3], cA, m2);
            fma4(accA[4], cA, m1);
            fma4(accA[5], cA, cB);
            fma4(accA[6], cA, p1);
            fma4(accA[7], cA, p2);
            fma4(accB[0], cB, cB);
            fma4(accB[1], cB, p1);
            fma4(accB[2], cB, p2);
        }
        // rel row 2: dx {-2..2} -> accA[8..12]; accB[3..7]
        {
            float4 m2 = lp[262], m1 = lp[263], v0 = lp[264], p1 = lp[265], p2 = lp[266];
            fma4(accA[8],  cA, m2);
            fma4(accA[9],  cA, m1);
            fma4(accA[10], cA, v0);
            fma4(accA[11], cA, p1);
            fma4(accA[12], cA, p2);
            fma4(accB[3], cB, m2);
            fma4(accB[4], cB, m1);
            fma4(accB[5], cB, v0);
            fma4(accB[6], cB, p1);
            fma4(accB[7], cB, p2);
        }
        // rel row 3: dx {-2..2} -> accB[8..12]
        {
            float4 m2 = lp[394], m1 = lp[395], v0 = lp[396], p1 = lp[397], p2 = lp[398];
            fma4(accB[8],  cB, m2);
            fma4(accB[9],  cB, m1);
            fma4(accB[10], cB, v0);
            fma4(accB[11], cB, p1);
            fma4(accB[12], cB, p2);
        }
    }

    // plain coalesced stores into this chunk's private slice
    float* cb = comb + (size_t)chunk * CSTRIDE;
    int pixA = b * PLANE + (y0 + 2 * r) * W + x;
    int pixB = pixA + W;
#pragma unroll
    for (int m = 0; m < NSHIFT; ++m) {
        cb[m * NPIX + pixA] = accA[m + 1];
        cb[m * NPIX + pixB] = accB[m + 1];
    }
    cb[NSHIFT * NPIX + pixA] = accA[0];
    cb[NSHIFT * NPIX + pixB] = accB[0];
}

// ---------------------------------------------------------------------------
// Kernel L: per-valid-pixel loss assembly + reduce.
// comb layout: [chunk][map][pix]; map 0..11 = shifted dots (S order),
// map 12 = normsq. Chunk sum folded in at load time (sum4c).
// ---------------------------------------------------------------------------
__device__ __forceinline__ float sum4c(const float* __restrict__ p) {
    return (p[0] + p[CSTRIDE]) + (p[2 * CSTRIDE] + p[3 * CSTRIDE]);
}

__global__ __launch_bounds__(256) void k_loss(const float* __restrict__ comb,
                                              const int* __restrict__ seg,
                                              const int* __restrict__ gtb,
                                              const int* __restrict__ cnt,
                                              const int* __restrict__ inc,
                                              float* __restrict__ out) {
    const float* dots   = comb;                  // + i*NPIX per map (chunk 0 slice)
    const float* normsq = comb + NSHIFT * NPIX;  // map 12 (chunk 0 slice)
    int idx = blockIdx.x * 256 + threadIdx.x;
    int b = idx >> 14;
    int rem = idx & (PLANE - 1);
    int y = rem >> 7;
    int x = rem & 127;

    // factor = inc_b ? 1/(24 * max(cnt_b,1) * scale_num) : 0  (uniform per block)
    int sn = 0;
#pragma unroll
    for (int b2 = 0; b2 < BATCH; b2++) sn += (inc[b2] != 0);
    if (sn < 1) sn = 1;
    int cb = cnt[b]; if (cb < 1) cb = 1;
    float factor = inc[b] ? 1.0f / (24.0f * (float)cb * (float)sn) : 0.0f;

    float val = 0.0f;
    if (y >= 2 && y < H - 2 && x >= 2 && x < W - 2) {
        int sp = seg[idx];
        int gp = gtb[idx];
        int s0 = (sp == 255) ? 0 : sp;
        int g0 = (gp == 255) ? 0 : gp;
        if (s0 > 0 && g0 > 0) {
            float np = fmaxf(sqrtf(sum4c(normsq + idx)), 1e-8f);
            float sum = 0.0f;
#pragma unroll
            for (int i = 0; i < NSHIFT; ++i) {
                int off = S_DY[i] * W + S_DX[i];
                // + shift: cos(p, p+d)
                {
                    float d  = sum4c(dots + i * NPIX + idx);
                    float nn = fmaxf(sqrtf(sum4c(normsq + idx + off)), 1e-8f);
                    float cosv = d / (np * nn);
                    int sq = seg[idx + off];
                    float lab = (sp == sq && sp < 2) ? 1.0f : 0.0f;
                    float tt = cosv - lab;
                    sum = fmaf(tt, tt, sum);
                }
                // - shift: cos(p, p-d) = dot_d(p-d)/(norm(p)norm(p-d))
                {
                    float d  = sum4c(dots + i * NPIX + idx - off);
                    float nn = fmaxf(sqrtf(sum4c(normsq + idx - off)), 1e-8f);
                    float cosv = d / (np * nn);
                    int sq = seg[idx - off];
                    float lab = (sp == sq && sp < 2) ? 1.0f : 0.0f;
                    float tt = cosv - lab;
                    sum = fmaf(tt, tt, sum);
                }
            }
            val = sum * factor;
        }
    }

    // block reduction: wave shuffle then LDS across 4 waves
    for (int o = 32; o > 0; o >>= 1)
        val += __shfl_down(val, o, 64);
    __shared__ float wsum[4];
    int lane = threadIdx.x & 63;
    int wid  = threadIdx.x >> 6;
    if (lane == 0) wsum[wid] = val;
    __syncthreads();
    if (threadIdx.x == 0) {
        float s = wsum[0] + wsum[1] + wsum[2] + wsum[3];
        atomicAdd(out, s);
    }
}

// ---------------------------------------------------------------------------
extern "C" void kernel_launch(void* const* d_in, const int* in_sizes, int n_in,
                              void* d_out, int out_size, void* d_ws, size_t ws_size,
                              hipStream_t stream) {
    const float* er  = (const float*)d_in[0];
    const int*   seg = (const int*)d_in[1];
    const int*   gtb = (const int*)d_in[2];
    float* out = (float*)d_out;

    float* ws   = (float*)d_ws;
    float* comb = ws;                                  // 4 * 13 * NPIX floats (27.3 MB)
    int*   cnt  = (int*)(comb + NCHUNK * CSTRIDE);     // 8 ints
    int*   inc  = cnt + 8;                             // 8 ints

    hipLaunchKernelGGL(k_prep, dim3(1), dim3(64), 0, stream, cnt, inc, out);
    hipLaunchKernelGGL(k_corr, dim3(NCORRB + NSTATB), dim3(256), 0, stream,
                       er, seg, gtb, comb, cnt, inc);
    hipLaunchKernelGGL(k_loss, dim3(NPIX / 256), dim3(256), 0, stream,
                       comb, seg, gtb, cnt, inc, out);
}

// Round 2
// 215.718 us; speedup vs baseline: 1.0267x; 1.0267x over previous
//
#include <hip/hip_runtime.h>
#include <math.h>

// Problem constants (fixed by setup_inputs)
#define BATCH 8
#define CH    256
#define H     128
#define W     128
#define PLANE (H * W)            // 16384
#define NPIX  (BATCH * PLANE)    // 131072
#define NSHIFT 12                // symmetric half of the 24 shifts
#define NMAPS  13                // 12 shifted dots + normsq
#define NCHUNK 4                 // channel chunks
#define CPC    (CH / NCHUNK)     // 64 channels per chunk
#define CSTRIDE (NMAPS * NPIX)   // floats per chunk slice (1703936)

// 12 "positive" shifts: dy>0 or (dy==0 && dx>0). Negatives recovered by symmetry.
static __device__ __constant__ int S_DY[NSHIFT] = {0,0,1,1,1,1,1,2,2,2,2,2};
static __device__ __constant__ int S_DX[NSHIFT] = {1,2,-2,-1,0,1,2,-2,-1,0,1,2};

// R2 retile: 8-row tiles, 512-thread blocks.
#define TROWS  8
#define NTILE  (H / TROWS)                       // 16
#define NCORRB (BATCH * NTILE * NCHUNK)          // 512 corr blocks (2/CU)
#define NSTATB (BATCH * 32)                      // 256 stats blocks (512 thr each)

__device__ __forceinline__ void fma4(float& acc, const float4& a, const float4& b) {
    acc = fmaf(a.x, b.x, acc);
    acc = fmaf(a.y, b.y, acc);
    acc = fmaf(a.z, b.z, acc);
    acc = fmaf(a.w, b.w, acc);
}

// ---------------------------------------------------------------------------
// Kernel P: tiny init only (comb written exactly once per address in k_corr).
// ---------------------------------------------------------------------------
__global__ __launch_bounds__(64) void k_prep(int* __restrict__ cnt,
                                             int* __restrict__ inc,
                                             float* __restrict__ out) {
    int t = threadIdx.x;
    if (t < 8) { cnt[t] = 0; inc[t] = 0; }
    if (t == 0) out[0] = 0.0f;
}

// ---------------------------------------------------------------------------
// Kernel C: fused correlation + per-image stats.
// Blocks [0, NCORRB): correlation. Grid decode: chunk(4) | tile(16) | b(8).
//   512 thr; each thread computes 2 adjacent output rows (block covers 8
//   rows, stages 10 rows x 4 channels as float4-per-pixel).
//   R2 changes vs R1:
//   - 8-row tile: halo amplification 1.5x -> 1.25x (FETCH 201 -> 168 MB)
//   - double-buffered LDS: ONE barrier per channel-quad instead of two
//     (m233: the stage+vmcnt+barrier drain was the structural stall)
//   - prefetch depth 2: quad k+2's global loads issue during quad k's
//     compute, committed to LDS one full compute phase later.
// Blocks [NCORRB, NCORRB+NSTATB): per-image cnt/inc stats (512 px/thr-block).
// __launch_bounds__(512,4): 4 waves/SIMD -> 2 blocks/CU, 128-VGPR budget.
// ---------------------------------------------------------------------------
__global__ __launch_bounds__(512, 4) void k_corr(const float* __restrict__ er,
                                                 const int* __restrict__ seg,
                                                 const int* __restrict__ gtb,
                                                 float* __restrict__ comb,
                                                 int* __restrict__ cnt,
                                                 int* __restrict__ inc) {
    __shared__ float4 lds[2][10][132];   // 2 buffers, 10 staged rows, x padded by 2/side
    int t = threadIdx.x;

    if (blockIdx.x >= NCORRB) {
        // ---- stats path ----
        int blk2 = blockIdx.x - NCORRB;
        int b = blk2 >> 5;
        int i = (blk2 & 31) * 512 + t;
        int my_cnt = 0, my_any = 0;
        {
            int s = seg[b * PLANE + i];
            int g = gtb[b * PLANE + i];
            int s0 = (s == 255) ? 0 : s;
            int g0 = (g == 255) ? 0 : g;
            if (s0 > 0 && g0 > 0) {
                my_any = 1;
                int y = i >> 7, x = i & 127;
                if (y >= 2 && y < H - 2 && x >= 2 && x < W - 2) my_cnt = 1;
            }
        }
        for (int o = 32; o > 0; o >>= 1) {
            my_cnt += __shfl_down(my_cnt, o, 64);
            my_any |= __shfl_down(my_any, o, 64);
        }
        __shared__ int sc[8], sa[8];
        int lane = t & 63, wid = t >> 6;
        if (lane == 0) { sc[wid] = my_cnt; sa[wid] = my_any; }
        __syncthreads();
        if (t == 0) {
            int c = 0, a = 0;
#pragma unroll
            for (int w2 = 0; w2 < 8; ++w2) { c += sc[w2]; a |= sa[w2]; }
            if (c) atomicAdd(&cnt[b], c);
            if (a) atomicOr(&inc[b], 1);
        }
        return;
    }

    // ---- correlation path ----
    int blk = blockIdx.x;
    int chunk = blk & 3;
    int tile  = (blk >> 2) & 15;
    int b     = blk >> 6;
    int y0 = tile * TROWS;           // block covers output rows y0..y0+7
    int c0 = chunk * CPC;
    int r = t >> 7;                  // thread handles output rows y0+2r, y0+2r+1
    int x = t & 127;

    // zero the x-pad slots of BOTH buffers once (first barrier makes visible)
    if (t < 80) {
        int bi = t / 40, rem = t % 40;
        int row = rem >> 2, col = rem & 3;
        int xs = (col < 2) ? col : (col + 128);   // 0,1,130,131
        lds[bi][row][xs] = make_float4(0.f, 0.f, 0.f, 0.f);
    }

    float accA[13], accB[13];
#pragma unroll
    for (int i = 0; i < 13; i++) { accA[i] = 0.0f; accB[i] = 0.0f; }

    const float* base = er + (size_t)b * CH * PLANE;

    // prefetch registers: up to 3 stage slots x 4 channels (slot 2: t<256 only)
    float pf[3][4];
    auto load_quad = [&](int c) {
#pragma unroll
        for (int k = 0; k < 3; ++k) {
            if (k < 2 || t < 256) {
                int s = t + k * 512;         // 0..1279
                int row = s >> 7;            // 0..9
                int xs = s & 127;
                int y = y0 + row;
                if (y < H) {
                    const float* p0 = base + (size_t)c * PLANE + y * W + xs;
                    pf[k][0] = p0[0];
                    pf[k][1] = p0[PLANE];
                    pf[k][2] = p0[2 * PLANE];
                    pf[k][3] = p0[3 * PLANE];
                } else {
                    pf[k][0] = 0.f; pf[k][1] = 0.f; pf[k][2] = 0.f; pf[k][3] = 0.f;
                }
            }
        }
    };
    auto commit_quad = [&](int bi) {
#pragma unroll
        for (int k = 0; k < 3; ++k) {
            if (k < 2 || t < 256) {
                int s = t + k * 512;
                int row = s >> 7;
                int xs = s & 127;
                lds[bi][row][xs + 2] = make_float4(pf[k][0], pf[k][1], pf[k][2], pf[k][3]);
            }
        }
    };

    const int iters = CPC / 4;       // 16
    // prologue: quad 0 -> buf0; quad 1 in flight
    load_quad(c0);
    commit_quad(0);
    load_quad(c0 + 4);

    auto iter = [&](int it, int cur) {
        __syncthreads();   // buf[cur] writes visible; buf[cur^1] reads (prev iter) done
        if (it + 1 < iters) commit_quad(cur ^ 1);          // vmcnt wait lands here
        if (it + 2 < iters) load_quad(c0 + 4 * (it + 2));  // overlaps compute below

        const float4* lp = &lds[cur][2 * r][x + 2];
        float4 cA = lp[0];               // (rel row 0, dx 0)
        float4 cB = lp[132];             // (rel row 1, dx 0)
        // rel row 0: dx {0,1,2} -> accA[0..2]
        {
            float4 v1 = lp[1], v2 = lp[2];
            fma4(accA[0], cA, cA);
            fma4(accA[1], cA, v1);
            fma4(accA[2], cA, v2);
        }
        // rel row 1: dx {-2..2} -> accA[3..7]; accB[0..2] (dx 0,1,2)
        {
            float4 m2 = lp[130], m1 = lp[131], p1 = lp[133], p2 = lp[134];
            fma4(accA[3], cA, m2);
            fma4(accA[4], cA, m1);
            fma4(accA[5], cA, cB);
            fma4(accA[6], cA, p1);
            fma4(accA[7], cA, p2);
            fma4(accB[0], cB, cB);
            fma4(accB[1], cB, p1);
            fma4(accB[2], cB, p2);
        }
        // rel row 2: dx {-2..2} -> accA[8..12]; accB[3..7]
        {
            float4 m2 = lp[262], m1 = lp[263], v0 = lp[264], p1 = lp[265], p2 = lp[266];
            fma4(accA[8],  cA, m2);
            fma4(accA[9],  cA, m1);
            fma4(accA[10], cA, v0);
            fma4(accA[11], cA, p1);
            fma4(accA[12], cA, p2);
            fma4(accB[3], cB, m2);
            fma4(accB[4], cB, m1);
            fma4(accB[5], cB, v0);
            fma4(accB[6], cB, p1);
            fma4(accB[7], cB, p2);
        }
        // rel row 3: dx {-2..2} -> accB[8..12]
        {
            float4 m2 = lp[394], m1 = lp[395], v0 = lp[396], p1 = lp[397], p2 = lp[398];
            fma4(accB[8],  cB, m2);
            fma4(accB[9],  cB, m1);
            fma4(accB[10], cB, v0);
            fma4(accB[11], cB, p1);
            fma4(accB[12], cB, p2);
        }
    };

    for (int it = 0; it < iters; it += 2) {
        iter(it, 0);
        iter(it + 1, 1);
    }

    // plain coalesced stores into this chunk's private slice
    float* cb = comb + (size_t)chunk * CSTRIDE;
    int pixA = b * PLANE + (y0 + 2 * r) * W + x;
    int pixB = pixA + W;
#pragma unroll
    for (int m = 0; m < NSHIFT; ++m) {
        cb[m * NPIX + pixA] = accA[m + 1];
        cb[m * NPIX + pixB] = accB[m + 1];
    }
    cb[NSHIFT * NPIX + pixA] = accA[0];
    cb[NSHIFT * NPIX + pixB] = accB[0];
}

// ---------------------------------------------------------------------------
// Kernel R: per-pixel reciprocal norm = 1/max(sqrt(sum_c normsq), 1e-8).
// Replaces 25 sqrtf + 24 fdiv per valid pixel in k_loss with 2 loads + 2 muls.
// ---------------------------------------------------------------------------
__global__ __launch_bounds__(256) void k_rn(const float* __restrict__ comb,
                                            float* __restrict__ rn) {
    int idx = blockIdx.x * 256 + threadIdx.x;
    const float* ns = comb + NSHIFT * NPIX;
    float s = (ns[idx] + ns[idx + CSTRIDE]) + (ns[idx + 2 * CSTRIDE] + ns[idx + 3 * CSTRIDE]);
    // 1/max(sqrt(s),1e-8): rsqrt, clamped at 1e8 (handles s==0 -> inf -> 1e8)
    rn[idx] = fminf(rsqrtf(s), 1e8f);
}

// ---------------------------------------------------------------------------
// Kernel L: per-valid-pixel loss assembly + reduce.
// comb layout: [chunk][map][pix]; maps 0..11 = shifted dots, 12 = normsq.
// Norms come precomputed from rn[] (reciprocal) -> no sqrt/div in the
// divergent region.
// ---------------------------------------------------------------------------
__device__ __forceinline__ float sum4c(const float* __restrict__ p) {
    return (p[0] + p[CSTRIDE]) + (p[2 * CSTRIDE] + p[3 * CSTRIDE]);
}

__global__ __launch_bounds__(256) void k_loss(const float* __restrict__ comb,
                                              const float* __restrict__ rn,
                                              const int* __restrict__ seg,
                                              const int* __restrict__ gtb,
                                              const int* __restrict__ cnt,
                                              const int* __restrict__ inc,
                                              float* __restrict__ out) {
    const float* dots = comb;                  // + i*NPIX per map (chunk 0 slice)
    int idx = blockIdx.x * 256 + threadIdx.x;
    int b = idx >> 14;
    int rem = idx & (PLANE - 1);
    int y = rem >> 7;
    int x = rem & 127;

    // factor = inc_b ? 1/(24 * max(cnt_b,1) * scale_num) : 0  (uniform per block)
    int sn = 0;
#pragma unroll
    for (int b2 = 0; b2 < BATCH; b2++) sn += (inc[b2] != 0);
    if (sn < 1) sn = 1;
    int cb = cnt[b]; if (cb < 1) cb = 1;
    float factor = inc[b] ? 1.0f / (24.0f * (float)cb * (float)sn) : 0.0f;

    float val = 0.0f;
    if (y >= 2 && y < H - 2 && x >= 2 && x < W - 2) {
        int sp = seg[idx];
        int gp = gtb[idx];
        int s0 = (sp == 255) ? 0 : sp;
        int g0 = (gp == 255) ? 0 : gp;
        if (s0 > 0 && g0 > 0) {
            float npr = rn[idx];
            float sum = 0.0f;
#pragma unroll
            for (int i = 0; i < NSHIFT; ++i) {
                int off = S_DY[i] * W + S_DX[i];
                // + shift: cos(p, p+d)
                {
                    float d  = sum4c(dots + i * NPIX + idx);
                    float cosv = d * (npr * rn[idx + off]);
                    int sq = seg[idx + off];
                    float lab = (sp == sq && sp < 2) ? 1.0f : 0.0f;
                    float tt = cosv - lab;
                    sum = fmaf(tt, tt, sum);
                }
                // - shift: cos(p, p-d) = dot_d(p-d)/(norm(p)norm(p-d))
                {
                    float d  = sum4c(dots + i * NPIX + idx - off);
                    float cosv = d * (npr * rn[idx - off]);
                    int sq = seg[idx - off];
                    float lab = (sp == sq && sp < 2) ? 1.0f : 0.0f;
                    float tt = cosv - lab;
                    sum = fmaf(tt, tt, sum);
                }
            }
            val = sum * factor;
        }
    }

    // block reduction: wave shuffle then LDS across 4 waves
    for (int o = 32; o > 0; o >>= 1)
        val += __shfl_down(val, o, 64);
    __shared__ float wsum[4];
    int lane = threadIdx.x & 63;
    int wid  = threadIdx.x >> 6;
    if (lane == 0) wsum[wid] = val;
    __syncthreads();
    if (threadIdx.x == 0) {
        float s = wsum[0] + wsum[1] + wsum[2] + wsum[3];
        atomicAdd(out, s);
    }
}

// ---------------------------------------------------------------------------
extern "C" void kernel_launch(void* const* d_in, const int* in_sizes, int n_in,
                              void* d_out, int out_size, void* d_ws, size_t ws_size,
                              hipStream_t stream) {
    const float* er  = (const float*)d_in[0];
    const int*   seg = (const int*)d_in[1];
    const int*   gtb = (const int*)d_in[2];
    float* out = (float*)d_out;

    float* ws   = (float*)d_ws;
    float* comb = ws;                                  // 4 * 13 * NPIX floats (27.3 MB)
    float* rn   = comb + NCHUNK * CSTRIDE;             // NPIX floats (0.5 MB)
    int*   cnt  = (int*)(rn + NPIX);                   // 8 ints
    int*   inc  = cnt + 8;                             // 8 ints

    hipLaunchKernelGGL(k_prep, dim3(1), dim3(64), 0, stream, cnt, inc, out);
    hipLaunchKernelGGL(k_corr, dim3(NCORRB + NSTATB), dim3(512), 0, stream,
                       er, seg, gtb, comb, cnt, inc);
    hipLaunchKernelGGL(k_rn, dim3(NPIX / 256), dim3(256), 0, stream, comb, rn);
    hipLaunchKernelGGL(k_loss, dim3(NPIX / 256), dim3(256), 0, stream,
                       comb, rn, seg, gtb, cnt, inc, out);
}